// Round 5
// baseline (768.429 us; speedup 1.0000x reference)
//
#include <hip/hip_runtime.h>

#define N_NODES 100000
#define N_EDGES 1600000
#define C_H     128
#define C_OUT   40
#define K_FC    384
#define BN_EPS  1e-5f

typedef unsigned int uint;

// ---------------------------------------------------------------- utilities
__global__ void zero_i32(int* p, int n) {
    int i = blockIdx.x * blockDim.x + threadIdx.x;
    if (i < n) p[i] = 0;
}

__global__ void count_deg(const int* __restrict__ erow, int* __restrict__ deg) {
    int e = blockIdx.x * blockDim.x + threadIdx.x;
    if (e < N_EDGES) atomicAdd(&deg[erow[e]], 1);
}

__global__ void compute_dinv(const int* __restrict__ deg, float* __restrict__ dinv) {
    int i = blockIdx.x * blockDim.x + threadIdx.x;
    if (i < N_NODES) dinv[i] = rsqrtf((float)deg[i] + 1.0f);
}

__global__ __launch_bounds__(1024) void scan_block(const int* __restrict__ deg,
                                                   int* __restrict__ excl,
                                                   int* __restrict__ bsums) {
    __shared__ int sm[1024];
    int i = blockIdx.x * 1024 + threadIdx.x;
    int v = (i < N_NODES) ? deg[i] : 0;
    sm[threadIdx.x] = v;
    __syncthreads();
    for (int off = 1; off < 1024; off <<= 1) {
        int add = (threadIdx.x >= off) ? sm[threadIdx.x - off] : 0;
        __syncthreads();
        sm[threadIdx.x] += add;
        __syncthreads();
    }
    if (i < N_NODES) excl[i] = sm[threadIdx.x] - v;
    if (threadIdx.x == 1023) bsums[blockIdx.x] = sm[1023];
}

__global__ void scan_sums(int* __restrict__ bs, int nb) {
    __shared__ int sm[128];
    int tid = threadIdx.x;
    if (tid < nb) sm[tid] = bs[tid];
    __syncthreads();
    if (tid == 0) {
        int acc = 0;
        for (int i = 0; i < nb; ++i) { int t = sm[i]; sm[i] = acc; acc += t; }
    }
    __syncthreads();
    if (tid < nb) bs[tid] = sm[tid];
}

__global__ __launch_bounds__(1024) void add_offsets(int* __restrict__ rowptr,
                                                    const int* __restrict__ bsums,
                                                    int* __restrict__ fill) {
    int i = blockIdx.x * 1024 + threadIdx.x;
    if (i < N_NODES) {
        int v = rowptr[i] + bsums[blockIdx.x];
        rowptr[i] = v;
        fill[i] = v;
    }
    if (blockIdx.x == 0 && threadIdx.x == 0) rowptr[N_NODES] = N_EDGES;
}

__global__ void fill_csr(const int* __restrict__ erow, const int* __restrict__ ecol,
                         int* __restrict__ fill, int* __restrict__ cols) {
    int e = blockIdx.x * blockDim.x + threadIdx.x;
    if (e < N_EDGES) {
        int r = erow[e];
        int p = atomicAdd(&fill[r], 1);
        cols[p] = ecol[e];
    }
}

// relu(bn(agg + b)) = relu(agg*s + t)
__global__ void bn_coef(const float* b1, const float* g1, const float* be1,
                        const float* m1, const float* v1,
                        const float* b2, const float* g2, const float* be2,
                        const float* m2, const float* v2,
                        float* s1, float* t1, float* s2, float* t2) {
    int f = threadIdx.x;
    float sa = g1[f] * rsqrtf(v1[f] + BN_EPS);
    s1[f] = sa;
    t1[f] = (b1[f] - m1[f]) * sa + be1[f];
    float sb = g2[f] * rsqrtf(v2[f] + BN_EPS);
    s2[f] = sb;
    t2[f] = (b2[f] - m2[f]) * sb + be2[f];
}

#define FMA4(A, S, V) \
    A.x = fmaf(S, V.x, A.x); A.y = fmaf(S, V.y, A.y); \
    A.z = fmaf(S, V.z, A.z); A.w = fmaf(S, V.w, A.w);

__device__ inline uint pack_bf16x2(float a, float b) {
    uint ua = __builtin_bit_cast(uint, a);
    uint ub = __builtin_bit_cast(uint, b);
    ua += 0x7fffu + ((ua >> 16) & 1u);   // RNE
    ub += 0x7fffu + ((ub >> 16) & 1u);
    return (ua >> 16) | (ub & 0xffff0000u);
}

// -------------------- GEMM + dinv prescale: Hs(bf16) = diag(dinv) * (X @ W)
__global__ __launch_bounds__(256) void gemm_scaled(const float* __restrict__ X,
                                                   const float* __restrict__ W,
                                                   const float* __restrict__ dinv,
                                                   uint* __restrict__ Hs) {
    __shared__ float wl[64 * 128];   // k-half of W  (32 KB)
    __shared__ float xl[32 * 68];    // 32 rows x 64 cols, stride 68

    const int tid = threadIdx.x;
    const int rg = tid >> 5;
    const int c4 = (tid & 31) << 2;
    const int rb = blockIdx.x * 32;
    const int r0 = rb + rg * 4;

    float4 acc0 = {0,0,0,0}, acc1 = {0,0,0,0}, acc2 = {0,0,0,0}, acc3 = {0,0,0,0};

    for (int half = 0; half < 2; ++half) {
        const int k0 = half * 64;
        __syncthreads();
        {
            const float4* W4 = (const float4*)(W + (size_t)k0 * 128);
            float4* wl4 = (float4*)wl;
            #pragma unroll
            for (int i = 0; i < 8; ++i) wl4[tid + i * 256] = W4[tid + i * 256];
        }
        #pragma unroll
        for (int i = 0; i < 2; ++i) {
            int f = tid + i * 256;
            int row = f >> 4, cc = f & 15;
            float4 v = *(const float4*)(X + (size_t)(rb + row) * 128 + k0 + cc * 4);
            *(float4*)&xl[row * 68 + cc * 4] = v;
        }
        __syncthreads();

        for (int k4 = 0; k4 < 16; ++k4) {
            const float* wr = wl + k4 * 4 * 128 + c4;
            float4 w0 = *(const float4*)(wr);
            float4 w1 = *(const float4*)(wr + 128);
            float4 w2 = *(const float4*)(wr + 256);
            float4 w3 = *(const float4*)(wr + 384);
            float4 xv0 = *(const float4*)&xl[(rg * 4 + 0) * 68 + k4 * 4];
            float4 xv1 = *(const float4*)&xl[(rg * 4 + 1) * 68 + k4 * 4];
            float4 xv2 = *(const float4*)&xl[(rg * 4 + 2) * 68 + k4 * 4];
            float4 xv3 = *(const float4*)&xl[(rg * 4 + 3) * 68 + k4 * 4];
            FMA4(acc0, xv0.x, w0) FMA4(acc0, xv0.y, w1) FMA4(acc0, xv0.z, w2) FMA4(acc0, xv0.w, w3)
            FMA4(acc1, xv1.x, w0) FMA4(acc1, xv1.y, w1) FMA4(acc1, xv1.z, w2) FMA4(acc1, xv1.w, w3)
            FMA4(acc2, xv2.x, w0) FMA4(acc2, xv2.y, w1) FMA4(acc2, xv2.z, w2) FMA4(acc2, xv2.w, w3)
            FMA4(acc3, xv3.x, w0) FMA4(acc3, xv3.y, w1) FMA4(acc3, xv3.z, w2) FMA4(acc3, xv3.w, w3)
        }
    }
    float d0 = dinv[r0], d1 = dinv[r0 + 1], d2 = dinv[r0 + 2], d3 = dinv[r0 + 3];
    uint2 o;
    o.x = pack_bf16x2(acc0.x * d0, acc0.y * d0);
    o.y = pack_bf16x2(acc0.z * d0, acc0.w * d0);
    *(uint2*)(Hs + (size_t)(r0 + 0) * 64 + (c4 >> 1)) = o;
    o.x = pack_bf16x2(acc1.x * d1, acc1.y * d1);
    o.y = pack_bf16x2(acc1.z * d1, acc1.w * d1);
    *(uint2*)(Hs + (size_t)(r0 + 1) * 64 + (c4 >> 1)) = o;
    o.x = pack_bf16x2(acc2.x * d2, acc2.y * d2);
    o.y = pack_bf16x2(acc2.z * d2, acc2.w * d2);
    *(uint2*)(Hs + (size_t)(r0 + 2) * 64 + (c4 >> 1)) = o;
    o.x = pack_bf16x2(acc3.x * d3, acc3.y * d3);
    o.y = pack_bf16x2(acc3.z * d3, acc3.w * d3);
    *(uint2*)(Hs + (size_t)(r0 + 3) * 64 + (c4 >> 1)) = o;
}

// -------------------- SpMM on prescaled bf16 Hs: one wave per row, 2ch/lane.
__global__ __launch_bounds__(256) void spmm_bn_relu3(
    const uint* __restrict__ Hs, const int* __restrict__ cols,
    const int* __restrict__ rowptr, const float* __restrict__ dinv,
    const float* __restrict__ s, const float* __restrict__ t,
    float* __restrict__ Y) {
    const int lane = threadIdx.x & 63;
    const int r = blockIdx.x * 4 + (threadIdx.x >> 6);

    uint vself = Hs[(size_t)r * 64 + lane];
    float accx = __builtin_bit_cast(float, vself << 16);
    float accy = __builtin_bit_cast(float, vself & 0xffff0000u);
    const float di = dinv[r];
    const int e0 = rowptr[r], e1 = rowptr[r + 1];
    int j = e0;
    const int nfull8 = e0 + ((e1 - e0) & ~7);
    for (; j < nfull8; j += 8) {
        uint v0 = Hs[(size_t)cols[j + 0] * 64 + lane];
        uint v1 = Hs[(size_t)cols[j + 1] * 64 + lane];
        uint v2 = Hs[(size_t)cols[j + 2] * 64 + lane];
        uint v3 = Hs[(size_t)cols[j + 3] * 64 + lane];
        uint v4 = Hs[(size_t)cols[j + 4] * 64 + lane];
        uint v5 = Hs[(size_t)cols[j + 5] * 64 + lane];
        uint v6 = Hs[(size_t)cols[j + 6] * 64 + lane];
        uint v7 = Hs[(size_t)cols[j + 7] * 64 + lane];
        accx += __builtin_bit_cast(float, v0 << 16);
        accy += __builtin_bit_cast(float, v0 & 0xffff0000u);
        accx += __builtin_bit_cast(float, v1 << 16);
        accy += __builtin_bit_cast(float, v1 & 0xffff0000u);
        accx += __builtin_bit_cast(float, v2 << 16);
        accy += __builtin_bit_cast(float, v2 & 0xffff0000u);
        accx += __builtin_bit_cast(float, v3 << 16);
        accy += __builtin_bit_cast(float, v3 & 0xffff0000u);
        accx += __builtin_bit_cast(float, v4 << 16);
        accy += __builtin_bit_cast(float, v4 & 0xffff0000u);
        accx += __builtin_bit_cast(float, v5 << 16);
        accy += __builtin_bit_cast(float, v5 & 0xffff0000u);
        accx += __builtin_bit_cast(float, v6 << 16);
        accy += __builtin_bit_cast(float, v6 & 0xffff0000u);
        accx += __builtin_bit_cast(float, v7 << 16);
        accy += __builtin_bit_cast(float, v7 & 0xffff0000u);
    }
    for (; j < e1; ++j) {
        uint v0 = Hs[(size_t)cols[j] * 64 + lane];
        accx += __builtin_bit_cast(float, v0 << 16);
        accy += __builtin_bit_cast(float, v0 & 0xffff0000u);
    }
    float2 sf = ((const float2*)s)[lane];
    float2 tf = ((const float2*)t)[lane];
    float2 o;
    o.x = fmaxf(fmaf(accx * di, sf.x, tf.x), 0.0f);
    o.y = fmaxf(fmaf(accy * di, sf.y, tf.y), 0.0f);
    ((float2*)Y)[(size_t)r * 64 + lane] = o;
}

// -------------------- final FC: out = [x0|x1|x2] @ fcW + fcb  (384 -> 40)
// 256 threads, 256 rows/block. lane = row offset, wave = 10-col group.
// X read straight from global (no LDS); only the 2.5 KB W^T chunk is staged.
// wt reads are wave-uniform -> LDS broadcast, conflict-free.
__global__ __launch_bounds__(256) void final_gemm4(
    const float* __restrict__ X0, const float* __restrict__ X1,
    const float* __restrict__ X2, const float* __restrict__ fcW,
    const float* __restrict__ fcb, float* __restrict__ out) {
    __shared__ float wt[40 * 16];    // wt[c][kk]

    const int t = threadIdx.x;
    const int lane = t & 63;
    const int w = t >> 6;            // col group: cols w*10 .. w*10+9
    const int rbase = blockIdx.x * 256;

    float acc[4][10];
    #pragma unroll
    for (int rr = 0; rr < 4; ++rr)
        #pragma unroll
        for (int c = 0; c < 10; ++c) acc[rr][c] = 0.0f;

    const float* segs[3] = {X0, X1, X2};

    for (int ch = 0; ch < 24; ++ch) {
        const int k0 = ch * 16;
        const float* xseg = segs[k0 >> 7];
        const int koff = k0 & 127;
        __syncthreads();
        // stage W^T chunk: 640 floats
        #pragma unroll
        for (int i = 0; i < 3; ++i) {
            int idx = t + i * 256;
            if (idx < 640) {
                int c = idx % 40, kk = idx / 40;
                wt[c * 16 + kk] = fcW[(size_t)(k0 + kk) * 40 + c];
            }
        }
        __syncthreads();

        // load X rows (4 rows per thread) straight from global
        float4 xv[4][4];
        #pragma unroll
        for (int rr = 0; rr < 4; ++rr) {
            int r = rbase + rr * 64 + lane;
            const float* xp = xseg + (size_t)r * 128 + koff;
            #pragma unroll
            for (int kk4 = 0; kk4 < 4; ++kk4) {
                float4 v = {0, 0, 0, 0};
                if (r < N_NODES) v = *(const float4*)(xp + kk4 * 4);
                xv[rr][kk4] = v;
            }
        }
        #pragma unroll
        for (int kk4 = 0; kk4 < 4; ++kk4) {
            #pragma unroll
            for (int c = 0; c < 10; ++c) {
                float4 wv = *(const float4*)&wt[(w * 10 + c) * 16 + kk4 * 4];
                #pragma unroll
                for (int rr = 0; rr < 4; ++rr) {
                    acc[rr][c] = fmaf(xv[rr][kk4].x, wv.x, acc[rr][c]);
                    acc[rr][c] = fmaf(xv[rr][kk4].y, wv.y, acc[rr][c]);
                    acc[rr][c] = fmaf(xv[rr][kk4].z, wv.z, acc[rr][c]);
                    acc[rr][c] = fmaf(xv[rr][kk4].w, wv.w, acc[rr][c]);
                }
            }
        }
    }

    #pragma unroll
    for (int rr = 0; rr < 4; ++rr) {
        int r = rbase + rr * 64 + lane;
        if (r < N_NODES) {
            #pragma unroll
            for (int c2 = 0; c2 < 5; ++c2) {
                float2 o;
                o.x = acc[rr][c2 * 2 + 0] + fcb[w * 10 + c2 * 2 + 0];
                o.y = acc[rr][c2 * 2 + 1] + fcb[w * 10 + c2 * 2 + 1];
                *(float2*)(out + (size_t)r * 40 + w * 10 + c2 * 2) = o;
            }
        }
    }
}

// ---------------------------------------------------------------------------
extern "C" void kernel_launch(void* const* d_in, const int* in_sizes, int n_in,
                              void* d_out, int out_size, void* d_ws, size_t ws_size,
                              hipStream_t stream) {
    const float* x   = (const float*)d_in[0];
    const int*   ei  = (const int*)d_in[1];
    const int* e_row = ei;
    const int* e_col = ei + N_EDGES;
    const float* W1  = (const float*)d_in[2];
    const float* b1  = (const float*)d_in[3];
    const float* W2  = (const float*)d_in[4];
    const float* b2  = (const float*)d_in[5];
    const float* g1  = (const float*)d_in[6];
    const float* be1 = (const float*)d_in[7];
    const float* m1  = (const float*)d_in[8];
    const float* v1  = (const float*)d_in[9];
    const float* g2  = (const float*)d_in[10];
    const float* be2 = (const float*)d_in[11];
    const float* m2  = (const float*)d_in[12];
    const float* v2  = (const float*)d_in[13];
    const float* fcW = (const float*)d_in[14];
    const float* fcb = (const float*)d_in[15];
    float* out = (float*)d_out;

    char* ws = (char*)d_ws;
    size_t off = 0;
    auto alloc = [&](size_t b) {
        char* p = ws + off;
        off += (b + 255) & ~(size_t)255;
        return p;
    };
    uint*  h      = (uint*)alloc((size_t)N_NODES * C_H * 2);   // bf16 Hs
    float* x1     = (float*)alloc((size_t)N_NODES * C_H * 4);
    float* x2     = (float*)alloc((size_t)N_NODES * C_H * 4);
    int*   deg    = (int*)alloc(N_NODES * 4);
    float* dinv   = (float*)alloc(N_NODES * 4);
    int*   rowptr = (int*)alloc((N_NODES + 1) * 4);
    int*   fillc  = (int*)alloc(N_NODES * 4);
    int*   cols   = (int*)alloc((size_t)N_EDGES * 4);
    int*   bsums  = (int*)alloc(128 * 4);
    float* coef   = (float*)alloc(512 * 4);
    float* s1 = coef, *t1 = coef + 128, *s2 = coef + 256, *t2 = coef + 384;

    const int nb_scan = (N_NODES + 1023) / 1024;

    zero_i32<<<(N_NODES + 255) / 256, 256, 0, stream>>>(deg, N_NODES);
    count_deg<<<(N_EDGES + 255) / 256, 256, 0, stream>>>(e_row, deg);
    compute_dinv<<<(N_NODES + 255) / 256, 256, 0, stream>>>(deg, dinv);
    scan_block<<<nb_scan, 1024, 0, stream>>>(deg, rowptr, bsums);
    scan_sums<<<1, 128, 0, stream>>>(bsums, nb_scan);
    add_offsets<<<nb_scan, 1024, 0, stream>>>(rowptr, bsums, fillc);
    fill_csr<<<(N_EDGES + 255) / 256, 256, 0, stream>>>(e_row, e_col, fillc, cols);
    bn_coef<<<1, 128, 0, stream>>>(b1, g1, be1, m1, v1, b2, g2, be2, m2, v2,
                                   s1, t1, s2, t2);

    gemm_scaled<<<N_NODES / 32, 256, 0, stream>>>(x, W1, dinv, h);
    spmm_bn_relu3<<<N_NODES / 4, 256, 0, stream>>>(h, cols, rowptr, dinv, s1, t1, x1);
    gemm_scaled<<<N_NODES / 32, 256, 0, stream>>>(x1, W2, dinv, h);
    spmm_bn_relu3<<<N_NODES / 4, 256, 0, stream>>>(h, cols, rowptr, dinv, s2, t2, x2);
    final_gemm4<<<(N_NODES + 255) / 256, 256, 0, stream>>>(x, x1, x2, fcW, fcb, out);
}

// Round 6
// 659.588 us; speedup vs baseline: 1.1650x; 1.1650x over previous
//
#include <hip/hip_runtime.h>

#define N_NODES 100000
#define N_EDGES 1600000
#define C_H     128
#define C_OUT   40
#define K_FC    384
#define BN_EPS  1e-5f

typedef unsigned int uint;

// ---------------------------------------------------------------- utilities
__global__ void zero_i32(int* p, int n) {
    int i = blockIdx.x * blockDim.x + threadIdx.x;
    if (i < n) p[i] = 0;
}

__global__ void count_deg(const int* __restrict__ erow, int* __restrict__ deg) {
    int e = blockIdx.x * blockDim.x + threadIdx.x;
    if (e < N_EDGES) atomicAdd(&deg[erow[e]], 1);
}

__global__ void compute_dinv(const int* __restrict__ deg, float* __restrict__ dinv) {
    int i = blockIdx.x * blockDim.x + threadIdx.x;
    if (i < N_NODES) dinv[i] = rsqrtf((float)deg[i] + 1.0f);
}

__global__ __launch_bounds__(1024) void scan_block(const int* __restrict__ deg,
                                                   int* __restrict__ excl,
                                                   int* __restrict__ bsums) {
    __shared__ int sm[1024];
    int i = blockIdx.x * 1024 + threadIdx.x;
    int v = (i < N_NODES) ? deg[i] : 0;
    sm[threadIdx.x] = v;
    __syncthreads();
    for (int off = 1; off < 1024; off <<= 1) {
        int add = (threadIdx.x >= off) ? sm[threadIdx.x - off] : 0;
        __syncthreads();
        sm[threadIdx.x] += add;
        __syncthreads();
    }
    if (i < N_NODES) excl[i] = sm[threadIdx.x] - v;
    if (threadIdx.x == 1023) bsums[blockIdx.x] = sm[1023];
}

__global__ void scan_sums(int* __restrict__ bs, int nb) {
    __shared__ int sm[128];
    int tid = threadIdx.x;
    if (tid < nb) sm[tid] = bs[tid];
    __syncthreads();
    if (tid == 0) {
        int acc = 0;
        for (int i = 0; i < nb; ++i) { int t = sm[i]; sm[i] = acc; acc += t; }
    }
    __syncthreads();
    if (tid < nb) bs[tid] = sm[tid];
}

__global__ __launch_bounds__(1024) void add_offsets(int* __restrict__ rowptr,
                                                    const int* __restrict__ bsums,
                                                    int* __restrict__ fill) {
    int i = blockIdx.x * 1024 + threadIdx.x;
    if (i < N_NODES) {
        int v = rowptr[i] + bsums[blockIdx.x];
        rowptr[i] = v;
        fill[i] = v;
    }
    if (blockIdx.x == 0 && threadIdx.x == 0) rowptr[N_NODES] = N_EDGES;
}

__global__ void fill_csr(const int* __restrict__ erow, const int* __restrict__ ecol,
                         int* __restrict__ fill, int* __restrict__ cols) {
    int e = blockIdx.x * blockDim.x + threadIdx.x;
    if (e < N_EDGES) {
        int r = erow[e];
        int p = atomicAdd(&fill[r], 1);
        cols[p] = ecol[e];
    }
}

// relu(bn(agg + b)) = relu(agg*s + t)
__global__ void bn_coef(const float* b1, const float* g1, const float* be1,
                        const float* m1, const float* v1,
                        const float* b2, const float* g2, const float* be2,
                        const float* m2, const float* v2,
                        float* s1, float* t1, float* s2, float* t2) {
    int f = threadIdx.x;
    float sa = g1[f] * rsqrtf(v1[f] + BN_EPS);
    s1[f] = sa;
    t1[f] = (b1[f] - m1[f]) * sa + be1[f];
    float sb = g2[f] * rsqrtf(v2[f] + BN_EPS);
    s2[f] = sb;
    t2[f] = (b2[f] - m2[f]) * sb + be2[f];
}

#define FMA4(A, S, V) \
    A.x = fmaf(S, V.x, A.x); A.y = fmaf(S, V.y, A.y); \
    A.z = fmaf(S, V.z, A.z); A.w = fmaf(S, V.w, A.w);

__device__ inline uint pack_bf16x2(float a, float b) {
    uint ua = __builtin_bit_cast(uint, a);
    uint ub = __builtin_bit_cast(uint, b);
    ua += 0x7fffu + ((ua >> 16) & 1u);   // RNE
    ub += 0x7fffu + ((ub >> 16) & 1u);
    return (ua >> 16) | (ub & 0xffff0000u);
}

// -------------------- GEMM + dinv prescale: Hs(bf16) = diag(dinv) * (X @ W)
__global__ __launch_bounds__(256) void gemm_scaled(const float* __restrict__ X,
                                                   const float* __restrict__ W,
                                                   const float* __restrict__ dinv,
                                                   uint* __restrict__ Hs) {
    __shared__ float wl[64 * 128];   // k-half of W  (32 KB)
    __shared__ float xl[32 * 68];    // 32 rows x 64 cols, stride 68

    const int tid = threadIdx.x;
    const int rg = tid >> 5;
    const int c4 = (tid & 31) << 2;
    const int rb = blockIdx.x * 32;
    const int r0 = rb + rg * 4;

    float4 acc0 = {0,0,0,0}, acc1 = {0,0,0,0}, acc2 = {0,0,0,0}, acc3 = {0,0,0,0};

    for (int half = 0; half < 2; ++half) {
        const int k0 = half * 64;
        __syncthreads();
        {
            const float4* W4 = (const float4*)(W + (size_t)k0 * 128);
            float4* wl4 = (float4*)wl;
            #pragma unroll
            for (int i = 0; i < 8; ++i) wl4[tid + i * 256] = W4[tid + i * 256];
        }
        #pragma unroll
        for (int i = 0; i < 2; ++i) {
            int f = tid + i * 256;
            int row = f >> 4, cc = f & 15;
            float4 v = *(const float4*)(X + (size_t)(rb + row) * 128 + k0 + cc * 4);
            *(float4*)&xl[row * 68 + cc * 4] = v;
        }
        __syncthreads();

        for (int k4 = 0; k4 < 16; ++k4) {
            const float* wr = wl + k4 * 4 * 128 + c4;
            float4 w0 = *(const float4*)(wr);
            float4 w1 = *(const float4*)(wr + 128);
            float4 w2 = *(const float4*)(wr + 256);
            float4 w3 = *(const float4*)(wr + 384);
            float4 xv0 = *(const float4*)&xl[(rg * 4 + 0) * 68 + k4 * 4];
            float4 xv1 = *(const float4*)&xl[(rg * 4 + 1) * 68 + k4 * 4];
            float4 xv2 = *(const float4*)&xl[(rg * 4 + 2) * 68 + k4 * 4];
            float4 xv3 = *(const float4*)&xl[(rg * 4 + 3) * 68 + k4 * 4];
            FMA4(acc0, xv0.x, w0) FMA4(acc0, xv0.y, w1) FMA4(acc0, xv0.z, w2) FMA4(acc0, xv0.w, w3)
            FMA4(acc1, xv1.x, w0) FMA4(acc1, xv1.y, w1) FMA4(acc1, xv1.z, w2) FMA4(acc1, xv1.w, w3)
            FMA4(acc2, xv2.x, w0) FMA4(acc2, xv2.y, w1) FMA4(acc2, xv2.z, w2) FMA4(acc2, xv2.w, w3)
            FMA4(acc3, xv3.x, w0) FMA4(acc3, xv3.y, w1) FMA4(acc3, xv3.z, w2) FMA4(acc3, xv3.w, w3)
        }
    }
    float d0 = dinv[r0], d1 = dinv[r0 + 1], d2 = dinv[r0 + 2], d3 = dinv[r0 + 3];
    uint2 o;
    o.x = pack_bf16x2(acc0.x * d0, acc0.y * d0);
    o.y = pack_bf16x2(acc0.z * d0, acc0.w * d0);
    *(uint2*)(Hs + (size_t)(r0 + 0) * 64 + (c4 >> 1)) = o;
    o.x = pack_bf16x2(acc1.x * d1, acc1.y * d1);
    o.y = pack_bf16x2(acc1.z * d1, acc1.w * d1);
    *(uint2*)(Hs + (size_t)(r0 + 1) * 64 + (c4 >> 1)) = o;
    o.x = pack_bf16x2(acc2.x * d2, acc2.y * d2);
    o.y = pack_bf16x2(acc2.z * d2, acc2.w * d2);
    *(uint2*)(Hs + (size_t)(r0 + 2) * 64 + (c4 >> 1)) = o;
    o.x = pack_bf16x2(acc3.x * d3, acc3.y * d3);
    o.y = pack_bf16x2(acc3.z * d3, acc3.w * d3);
    *(uint2*)(Hs + (size_t)(r0 + 3) * 64 + (c4 >> 1)) = o;
}

// -------------------- SpMM on prescaled bf16 Hs: one wave per row, 2ch/lane.
// (R4-known-good unroll-4 version)
__global__ __launch_bounds__(256) void spmm_bn_relu3(
    const uint* __restrict__ Hs, const int* __restrict__ cols,
    const int* __restrict__ rowptr, const float* __restrict__ dinv,
    const float* __restrict__ s, const float* __restrict__ t,
    float* __restrict__ Y) {
    const int lane = threadIdx.x & 63;
    const int r = blockIdx.x * 4 + (threadIdx.x >> 6);

    uint vself = Hs[(size_t)r * 64 + lane];
    float accx = __builtin_bit_cast(float, vself << 16);
    float accy = __builtin_bit_cast(float, vself & 0xffff0000u);
    const float di = dinv[r];
    const int e0 = rowptr[r], e1 = rowptr[r + 1];
    int j = e0;
    const int nfull = e0 + ((e1 - e0) & ~3);
    for (; j < nfull; j += 4) {
        int c0 = cols[j], c1 = cols[j + 1], c2 = cols[j + 2], c3 = cols[j + 3];
        uint v0 = Hs[(size_t)c0 * 64 + lane];
        uint v1 = Hs[(size_t)c1 * 64 + lane];
        uint v2 = Hs[(size_t)c2 * 64 + lane];
        uint v3 = Hs[(size_t)c3 * 64 + lane];
        accx += __builtin_bit_cast(float, v0 << 16);
        accy += __builtin_bit_cast(float, v0 & 0xffff0000u);
        accx += __builtin_bit_cast(float, v1 << 16);
        accy += __builtin_bit_cast(float, v1 & 0xffff0000u);
        accx += __builtin_bit_cast(float, v2 << 16);
        accy += __builtin_bit_cast(float, v2 & 0xffff0000u);
        accx += __builtin_bit_cast(float, v3 << 16);
        accy += __builtin_bit_cast(float, v3 & 0xffff0000u);
    }
    for (; j < e1; ++j) {
        uint v0 = Hs[(size_t)cols[j] * 64 + lane];
        accx += __builtin_bit_cast(float, v0 << 16);
        accy += __builtin_bit_cast(float, v0 & 0xffff0000u);
    }
    float2 sf = ((const float2*)s)[lane];
    float2 tf = ((const float2*)t)[lane];
    float2 o;
    o.x = fmaxf(fmaf(accx * di, sf.x, tf.x), 0.0f);
    o.y = fmaxf(fmaf(accy * di, sf.y, tf.y), 0.0f);
    ((float2*)Y)[(size_t)r * 64 + lane] = o;
}

// -------------------- final FC: out = [x0|x1|x2] @ fcW + fcb  (384 -> 40)
// 256 threads, 128 rows/block, grid 782. Coalesced global->LDS staging;
// xs stride 17 (odd) -> compute-side lane-stride-17 scalar reads hit all 32
// banks (2 lanes/bank = free). Thread = (lane=row, wave=10-col group),
// 2 rows x 10 cols per thread. wt reads wave-uniform b128 (broadcast).
__global__ __launch_bounds__(256) void final_gemm5(
    const float* __restrict__ X0, const float* __restrict__ X1,
    const float* __restrict__ X2, const float* __restrict__ fcW,
    const float* __restrict__ fcb, float* __restrict__ out) {
    __shared__ float xs[128 * 17];   // 8704 B
    __shared__ float wt[40 * 16];    // 2560 B, wt[c][kk]

    const int t = threadIdx.x;
    const int lane = t & 63;
    const int w = t >> 6;            // col group: cols w*10 .. w*10+9
    const int rbase = blockIdx.x * 128;

    float acc[2][10];
    #pragma unroll
    for (int rr = 0; rr < 2; ++rr)
        #pragma unroll
        for (int c = 0; c < 10; ++c) acc[rr][c] = 0.0f;

    const float* segs[3] = {X0, X1, X2};

    for (int ch = 0; ch < 24; ++ch) {
        const int k0 = ch * 16;
        const float* xseg = segs[k0 >> 7];
        const int koff = k0 & 127;
        __syncthreads();
        // stage X: 128 rows x 16 k = 512 float4, 2/thread, coalesced
        // (4 consecutive lanes cover one row's 64 B)
        #pragma unroll
        for (int i = 0; i < 2; ++i) {
            int f = t + i * 256;
            int row = f >> 2, cc = f & 3;
            int r = rbase + row;
            float4 v = {0, 0, 0, 0};
            if (r < N_NODES)
                v = *(const float4*)(xseg + (size_t)r * 128 + koff + cc * 4);
            xs[row * 17 + cc * 4 + 0] = v.x;
            xs[row * 17 + cc * 4 + 1] = v.y;
            xs[row * 17 + cc * 4 + 2] = v.z;
            xs[row * 17 + cc * 4 + 3] = v.w;
        }
        // stage W^T chunk: 640 floats
        #pragma unroll
        for (int i = 0; i < 3; ++i) {
            int idx = t + i * 256;
            if (idx < 640) {
                int c = idx % 40, kk = idx / 40;
                wt[c * 16 + kk] = fcW[(size_t)(k0 + kk) * 40 + c];
            }
        }
        __syncthreads();

        #pragma unroll
        for (int kk4 = 0; kk4 < 4; ++kk4) {
            float4 wv[10];
            #pragma unroll
            for (int c = 0; c < 10; ++c)
                wv[c] = *(const float4*)&wt[(w * 10 + c) * 16 + kk4 * 4];
            #pragma unroll
            for (int i = 0; i < 4; ++i) {
                float xa = xs[(lane) * 17 + kk4 * 4 + i];
                float xb = xs[(64 + lane) * 17 + kk4 * 4 + i];
                #pragma unroll
                for (int c = 0; c < 10; ++c) {
                    float wc = (i == 0) ? wv[c].x : (i == 1) ? wv[c].y
                             : (i == 2) ? wv[c].z : wv[c].w;
                    acc[0][c] = fmaf(xa, wc, acc[0][c]);
                    acc[1][c] = fmaf(xb, wc, acc[1][c]);
                }
            }
        }
    }

    #pragma unroll
    for (int rr = 0; rr < 2; ++rr) {
        int r = rbase + rr * 64 + lane;
        if (r < N_NODES) {
            #pragma unroll
            for (int c2 = 0; c2 < 5; ++c2) {
                float2 o;
                o.x = acc[rr][c2 * 2 + 0] + fcb[w * 10 + c2 * 2 + 0];
                o.y = acc[rr][c2 * 2 + 1] + fcb[w * 10 + c2 * 2 + 1];
                *(float2*)(out + (size_t)r * 40 + w * 10 + c2 * 2) = o;
            }
        }
    }
}

// ---------------------------------------------------------------------------
extern "C" void kernel_launch(void* const* d_in, const int* in_sizes, int n_in,
                              void* d_out, int out_size, void* d_ws, size_t ws_size,
                              hipStream_t stream) {
    const float* x   = (const float*)d_in[0];
    const int*   ei  = (const int*)d_in[1];
    const int* e_row = ei;
    const int* e_col = ei + N_EDGES;
    const float* W1  = (const float*)d_in[2];
    const float* b1  = (const float*)d_in[3];
    const float* W2  = (const float*)d_in[4];
    const float* b2  = (const float*)d_in[5];
    const float* g1  = (const float*)d_in[6];
    const float* be1 = (const float*)d_in[7];
    const float* m1  = (const float*)d_in[8];
    const float* v1  = (const float*)d_in[9];
    const float* g2  = (const float*)d_in[10];
    const float* be2 = (const float*)d_in[11];
    const float* m2  = (const float*)d_in[12];
    const float* v2  = (const float*)d_in[13];
    const float* fcW = (const float*)d_in[14];
    const float* fcb = (const float*)d_in[15];
    float* out = (float*)d_out;

    char* ws = (char*)d_ws;
    size_t off = 0;
    auto alloc = [&](size_t b) {
        char* p = ws + off;
        off += (b + 255) & ~(size_t)255;
        return p;
    };
    uint*  h      = (uint*)alloc((size_t)N_NODES * C_H * 2);   // bf16 Hs
    float* x1     = (float*)alloc((size_t)N_NODES * C_H * 4);
    float* x2     = (float*)alloc((size_t)N_NODES * C_H * 4);
    int*   deg    = (int*)alloc(N_NODES * 4);
    float* dinv   = (float*)alloc(N_NODES * 4);
    int*   rowptr = (int*)alloc((N_NODES + 1) * 4);
    int*   fillc  = (int*)alloc(N_NODES * 4);
    int*   cols   = (int*)alloc((size_t)N_EDGES * 4);
    int*   bsums  = (int*)alloc(128 * 4);
    float* coef   = (float*)alloc(512 * 4);
    float* s1 = coef, *t1 = coef + 128, *s2 = coef + 256, *t2 = coef + 384;

    const int nb_scan = (N_NODES + 1023) / 1024;

    zero_i32<<<(N_NODES + 255) / 256, 256, 0, stream>>>(deg, N_NODES);
    count_deg<<<(N_EDGES + 255) / 256, 256, 0, stream>>>(e_row, deg);
    compute_dinv<<<(N_NODES + 255) / 256, 256, 0, stream>>>(deg, dinv);
    scan_block<<<nb_scan, 1024, 0, stream>>>(deg, rowptr, bsums);
    scan_sums<<<1, 128, 0, stream>>>(bsums, nb_scan);
    add_offsets<<<nb_scan, 1024, 0, stream>>>(rowptr, bsums, fillc);
    fill_csr<<<(N_EDGES + 255) / 256, 256, 0, stream>>>(e_row, e_col, fillc, cols);
    bn_coef<<<1, 128, 0, stream>>>(b1, g1, be1, m1, v1, b2, g2, be2, m2, v2,
                                   s1, t1, s2, t2);

    gemm_scaled<<<N_NODES / 32, 256, 0, stream>>>(x, W1, dinv, h);
    spmm_bn_relu3<<<N_NODES / 4, 256, 0, stream>>>(h, cols, rowptr, dinv, s1, t1, x1);
    gemm_scaled<<<N_NODES / 32, 256, 0, stream>>>(x1, W2, dinv, h);
    spmm_bn_relu3<<<N_NODES / 4, 256, 0, stream>>>(h, cols, rowptr, dinv, s2, t2, x2);
    final_gemm5<<<(N_NODES + 127) / 128, 256, 0, stream>>>(x, x1, x2, fcW, fcb, out);
}

// Round 7
// 541.733 us; speedup vs baseline: 1.4185x; 1.2176x over previous
//
#include <hip/hip_runtime.h>

#define N_NODES 100000
#define N_EDGES 1600000
#define C_H     128
#define C_OUT   40
#define K_FC    384
#define BN_EPS  1e-5f
#define NB      391        // buckets: row >> 8
#define CHUNK   6144       // edges per binning workgroup

typedef unsigned int uint;

// ---------------------------------------------------------------- utilities
__global__ void zero_i32(int* p, int n) {
    int i = blockIdx.x * blockDim.x + threadIdx.x;
    if (i < n) p[i] = 0;
}

// -------- CSR build, stage 1: per-chunk LDS histogram over 391 buckets
__global__ __launch_bounds__(256) void bucket_count(const int* __restrict__ erow,
                                                    int* __restrict__ bcnt) {
    __shared__ int cnt[NB];
    for (int i = threadIdx.x; i < NB; i += 256) cnt[i] = 0;
    __syncthreads();
    const int c0 = blockIdx.x * CHUNK;
    const int c1 = min(c0 + CHUNK, N_EDGES);
    for (int e = c0 + threadIdx.x; e < c1; e += 256)
        atomicAdd(&cnt[erow[e] >> 8], 1);
    __syncthreads();
    for (int i = threadIdx.x; i < NB; i += 256)
        if (cnt[i]) atomicAdd(&bcnt[i], cnt[i]);
}

// -------- stage 2: exclusive scan of bucket counts (single WG)
__global__ __launch_bounds__(256) void scan_buckets(const int* __restrict__ bcnt,
                                                    int* __restrict__ bstart,
                                                    int* __restrict__ bfill) {
    __shared__ int sa[512], sb[512];
    const int t = threadIdx.x;
    int v0 = (t < NB) ? bcnt[t] : 0;
    int v1 = (t + 256 < NB) ? bcnt[t + 256] : 0;
    sa[t] = v0; sa[t + 256] = v1;
    __syncthreads();
    int* src = sa; int* dst = sb;
    for (int off = 1; off < 512; off <<= 1) {
        dst[t]       = src[t]       + (t >= off ? src[t - off] : 0);
        dst[t + 256] = src[t + 256] + (t + 256 >= off ? src[t + 256 - off] : 0);
        __syncthreads();
        int* tmp = src; src = dst; dst = tmp;
    }
    if (t < NB)       { bstart[t] = src[t] - v0;             bfill[t] = src[t] - v0; }
    if (t + 256 < NB) { bstart[t + 256] = src[t + 256] - v1; bfill[t + 256] = src[t + 256] - v1; }
    if (t == 0) bstart[NB] = N_EDGES;
}

// -------- stage 3: scatter (row,col) pairs into per-bucket dense ranges
__global__ __launch_bounds__(256) void bucket_bin(const int* __restrict__ erow,
                                                  const int* __restrict__ ecol,
                                                  int* __restrict__ bfill,
                                                  int2* __restrict__ pairs) {
    __shared__ int cnt[NB];
    __shared__ int lpos[NB];
    for (int i = threadIdx.x; i < NB; i += 256) cnt[i] = 0;
    __syncthreads();
    const int c0 = blockIdx.x * CHUNK;
    const int c1 = min(c0 + CHUNK, N_EDGES);
    for (int e = c0 + threadIdx.x; e < c1; e += 256)
        atomicAdd(&cnt[erow[e] >> 8], 1);
    __syncthreads();
    for (int i = threadIdx.x; i < NB; i += 256)
        lpos[i] = cnt[i] ? atomicAdd(&bfill[i], cnt[i]) : 0;
    __syncthreads();
    for (int e = c0 + threadIdx.x; e < c1; e += 256) {
        int r = erow[e], c = ecol[e];
        int p = atomicAdd(&lpos[r >> 8], 1);
        pairs[p] = make_int2(r, c);
    }
}

// -------- stage 4: per-bucket local sort -> rowptr, dinv, cols (one WG/bucket)
__global__ __launch_bounds__(256) void bucket_csr(const int2* __restrict__ pairs,
                                                  const int* __restrict__ bstart,
                                                  int* __restrict__ rowptr,
                                                  float* __restrict__ dinv,
                                                  int* __restrict__ colsg) {
    __shared__ int lcnt[256], sa[256], sb[256], lpos[256];
    const int b = blockIdx.x;
    const int t = threadIdx.x;
    const int p0 = bstart[b], p1 = bstart[b + 1];
    lcnt[t] = 0;
    __syncthreads();
    for (int i = p0 + t; i < p1; i += 256)
        atomicAdd(&lcnt[pairs[i].x & 255], 1);
    __syncthreads();
    sa[t] = lcnt[t];
    __syncthreads();
    int* src = sa; int* dst = sb;
    for (int off = 1; off < 256; off <<= 1) {
        dst[t] = src[t] + (t >= off ? src[t - off] : 0);
        __syncthreads();
        int* tmp = src; src = dst; dst = tmp;
    }
    const int excl = src[t] - lcnt[t];
    const int r = b * 256 + t;
    if (r < N_NODES) {
        rowptr[r] = p0 + excl;
        dinv[r] = rsqrtf((float)lcnt[t] + 1.0f);
    }
    if (b == NB - 1 && t == 0) rowptr[N_NODES] = N_EDGES;
    lpos[t] = excl;
    __syncthreads();
    for (int i = p0 + t; i < p1; i += 256) {
        int2 pr = pairs[i];
        int s = atomicAdd(&lpos[pr.x & 255], 1);
        colsg[p0 + s] = pr.y;
    }
}

// relu(bn(agg + b)) = relu(agg*s + t)
__global__ void bn_coef(const float* b1, const float* g1, const float* be1,
                        const float* m1, const float* v1,
                        const float* b2, const float* g2, const float* be2,
                        const float* m2, const float* v2,
                        float* s1, float* t1, float* s2, float* t2) {
    int f = threadIdx.x;
    float sa = g1[f] * rsqrtf(v1[f] + BN_EPS);
    s1[f] = sa;
    t1[f] = (b1[f] - m1[f]) * sa + be1[f];
    float sb = g2[f] * rsqrtf(v2[f] + BN_EPS);
    s2[f] = sb;
    t2[f] = (b2[f] - m2[f]) * sb + be2[f];
}

#define FMA4(A, S, V) \
    A.x = fmaf(S, V.x, A.x); A.y = fmaf(S, V.y, A.y); \
    A.z = fmaf(S, V.z, A.z); A.w = fmaf(S, V.w, A.w);

__device__ inline uint pack_bf16x2(float a, float b) {
    uint ua = __builtin_bit_cast(uint, a);
    uint ub = __builtin_bit_cast(uint, b);
    ua += 0x7fffu + ((ua >> 16) & 1u);   // RNE
    ub += 0x7fffu + ((ub >> 16) & 1u);
    return (ua >> 16) | (ub & 0xffff0000u);
}

// -------------------- GEMM + dinv prescale: Hs(bf16) = diag(dinv) * (X @ W)
__global__ __launch_bounds__(256) void gemm_scaled(const float* __restrict__ X,
                                                   const float* __restrict__ W,
                                                   const float* __restrict__ dinv,
                                                   uint* __restrict__ Hs) {
    __shared__ float wl[64 * 128];   // k-half of W  (32 KB)
    __shared__ float xl[32 * 68];    // 32 rows x 64 cols, stride 68

    const int tid = threadIdx.x;
    const int rg = tid >> 5;
    const int c4 = (tid & 31) << 2;
    const int rb = blockIdx.x * 32;
    const int r0 = rb + rg * 4;

    float4 acc0 = {0,0,0,0}, acc1 = {0,0,0,0}, acc2 = {0,0,0,0}, acc3 = {0,0,0,0};

    for (int half = 0; half < 2; ++half) {
        const int k0 = half * 64;
        __syncthreads();
        {
            const float4* W4 = (const float4*)(W + (size_t)k0 * 128);
            float4* wl4 = (float4*)wl;
            #pragma unroll
            for (int i = 0; i < 8; ++i) wl4[tid + i * 256] = W4[tid + i * 256];
        }
        #pragma unroll
        for (int i = 0; i < 2; ++i) {
            int f = tid + i * 256;
            int row = f >> 4, cc = f & 15;
            float4 v = *(const float4*)(X + (size_t)(rb + row) * 128 + k0 + cc * 4);
            *(float4*)&xl[row * 68 + cc * 4] = v;
        }
        __syncthreads();

        for (int k4 = 0; k4 < 16; ++k4) {
            const float* wr = wl + k4 * 4 * 128 + c4;
            float4 w0 = *(const float4*)(wr);
            float4 w1 = *(const float4*)(wr + 128);
            float4 w2 = *(const float4*)(wr + 256);
            float4 w3 = *(const float4*)(wr + 384);
            float4 xv0 = *(const float4*)&xl[(rg * 4 + 0) * 68 + k4 * 4];
            float4 xv1 = *(const float4*)&xl[(rg * 4 + 1) * 68 + k4 * 4];
            float4 xv2 = *(const float4*)&xl[(rg * 4 + 2) * 68 + k4 * 4];
            float4 xv3 = *(const float4*)&xl[(rg * 4 + 3) * 68 + k4 * 4];
            FMA4(acc0, xv0.x, w0) FMA4(acc0, xv0.y, w1) FMA4(acc0, xv0.z, w2) FMA4(acc0, xv0.w, w3)
            FMA4(acc1, xv1.x, w0) FMA4(acc1, xv1.y, w1) FMA4(acc1, xv1.z, w2) FMA4(acc1, xv1.w, w3)
            FMA4(acc2, xv2.x, w0) FMA4(acc2, xv2.y, w1) FMA4(acc2, xv2.z, w2) FMA4(acc2, xv2.w, w3)
            FMA4(acc3, xv3.x, w0) FMA4(acc3, xv3.y, w1) FMA4(acc3, xv3.z, w2) FMA4(acc3, xv3.w, w3)
        }
    }
    float d0 = dinv[r0], d1 = dinv[r0 + 1], d2 = dinv[r0 + 2], d3 = dinv[r0 + 3];
    uint2 o;
    o.x = pack_bf16x2(acc0.x * d0, acc0.y * d0);
    o.y = pack_bf16x2(acc0.z * d0, acc0.w * d0);
    *(uint2*)(Hs + (size_t)(r0 + 0) * 64 + (c4 >> 1)) = o;
    o.x = pack_bf16x2(acc1.x * d1, acc1.y * d1);
    o.y = pack_bf16x2(acc1.z * d1, acc1.w * d1);
    *(uint2*)(Hs + (size_t)(r0 + 1) * 64 + (c4 >> 1)) = o;
    o.x = pack_bf16x2(acc2.x * d2, acc2.y * d2);
    o.y = pack_bf16x2(acc2.z * d2, acc2.w * d2);
    *(uint2*)(Hs + (size_t)(r0 + 2) * 64 + (c4 >> 1)) = o;
    o.x = pack_bf16x2(acc3.x * d3, acc3.y * d3);
    o.y = pack_bf16x2(acc3.z * d3, acc3.w * d3);
    *(uint2*)(Hs + (size_t)(r0 + 3) * 64 + (c4 >> 1)) = o;
}

// -------------------- SpMM on prescaled bf16 Hs: one wave per row, 2ch/lane.
__global__ __launch_bounds__(256) void spmm_bn_relu3(
    const uint* __restrict__ Hs, const int* __restrict__ cols,
    const int* __restrict__ rowptr, const float* __restrict__ dinv,
    const float* __restrict__ s, const float* __restrict__ t,
    float* __restrict__ Y) {
    const int lane = threadIdx.x & 63;
    const int r = blockIdx.x * 4 + (threadIdx.x >> 6);

    uint vself = Hs[(size_t)r * 64 + lane];
    float accx = __builtin_bit_cast(float, vself << 16);
    float accy = __builtin_bit_cast(float, vself & 0xffff0000u);
    const float di = dinv[r];
    const int e0 = rowptr[r], e1 = rowptr[r + 1];
    int j = e0;
    const int nfull8 = e0 + ((e1 - e0) & ~7);
    for (; j < nfull8; j += 8) {
        uint v0 = Hs[(size_t)cols[j + 0] * 64 + lane];
        uint v1 = Hs[(size_t)cols[j + 1] * 64 + lane];
        uint v2 = Hs[(size_t)cols[j + 2] * 64 + lane];
        uint v3 = Hs[(size_t)cols[j + 3] * 64 + lane];
        uint v4 = Hs[(size_t)cols[j + 4] * 64 + lane];
        uint v5 = Hs[(size_t)cols[j + 5] * 64 + lane];
        uint v6 = Hs[(size_t)cols[j + 6] * 64 + lane];
        uint v7 = Hs[(size_t)cols[j + 7] * 64 + lane];
        accx += __builtin_bit_cast(float, v0 << 16);
        accy += __builtin_bit_cast(float, v0 & 0xffff0000u);
        accx += __builtin_bit_cast(float, v1 << 16);
        accy += __builtin_bit_cast(float, v1 & 0xffff0000u);
        accx += __builtin_bit_cast(float, v2 << 16);
        accy += __builtin_bit_cast(float, v2 & 0xffff0000u);
        accx += __builtin_bit_cast(float, v3 << 16);
        accy += __builtin_bit_cast(float, v3 & 0xffff0000u);
        accx += __builtin_bit_cast(float, v4 << 16);
        accy += __builtin_bit_cast(float, v4 & 0xffff0000u);
        accx += __builtin_bit_cast(float, v5 << 16);
        accy += __builtin_bit_cast(float, v5 & 0xffff0000u);
        accx += __builtin_bit_cast(float, v6 << 16);
        accy += __builtin_bit_cast(float, v6 & 0xffff0000u);
        accx += __builtin_bit_cast(float, v7 << 16);
        accy += __builtin_bit_cast(float, v7 & 0xffff0000u);
    }
    for (; j < e1; ++j) {
        uint v0 = Hs[(size_t)cols[j] * 64 + lane];
        accx += __builtin_bit_cast(float, v0 << 16);
        accy += __builtin_bit_cast(float, v0 & 0xffff0000u);
    }
    float2 sf = ((const float2*)s)[lane];
    float2 tf = ((const float2*)t)[lane];
    float2 o;
    o.x = fmaxf(fmaf(accx * di, sf.x, tf.x), 0.0f);
    o.y = fmaxf(fmaf(accy * di, sf.y, tf.y), 0.0f);
    ((float2*)Y)[(size_t)r * 64 + lane] = o;
}

// -------------------- final FC: out = [x0|x1|x2] @ fcW + fcb  (384 -> 40)
__global__ __launch_bounds__(256) void final_gemm5(
    const float* __restrict__ X0, const float* __restrict__ X1,
    const float* __restrict__ X2, const float* __restrict__ fcW,
    const float* __restrict__ fcb, float* __restrict__ out) {
    __shared__ float xs[128 * 17];   // 8704 B
    __shared__ float wt[40 * 16];    // 2560 B, wt[c][kk]

    const int t = threadIdx.x;
    const int lane = t & 63;
    const int w = t >> 6;
    const int rbase = blockIdx.x * 128;

    float acc[2][10];
    #pragma unroll
    for (int rr = 0; rr < 2; ++rr)
        #pragma unroll
        for (int c = 0; c < 10; ++c) acc[rr][c] = 0.0f;

    const float* segs[3] = {X0, X1, X2};

    for (int ch = 0; ch < 24; ++ch) {
        const int k0 = ch * 16;
        const float* xseg = segs[k0 >> 7];
        const int koff = k0 & 127;
        __syncthreads();
        #pragma unroll
        for (int i = 0; i < 2; ++i) {
            int f = t + i * 256;
            int row = f >> 2, cc = f & 3;
            int r = rbase + row;
            float4 v = {0, 0, 0, 0};
            if (r < N_NODES)
                v = *(const float4*)(xseg + (size_t)r * 128 + koff + cc * 4);
            xs[row * 17 + cc * 4 + 0] = v.x;
            xs[row * 17 + cc * 4 + 1] = v.y;
            xs[row * 17 + cc * 4 + 2] = v.z;
            xs[row * 17 + cc * 4 + 3] = v.w;
        }
        #pragma unroll
        for (int i = 0; i < 3; ++i) {
            int idx = t + i * 256;
            if (idx < 640) {
                int c = idx % 40, kk = idx / 40;
                wt[c * 16 + kk] = fcW[(size_t)(k0 + kk) * 40 + c];
            }
        }
        __syncthreads();

        #pragma unroll
        for (int kk4 = 0; kk4 < 4; ++kk4) {
            float4 wv[10];
            #pragma unroll
            for (int c = 0; c < 10; ++c)
                wv[c] = *(const float4*)&wt[(w * 10 + c) * 16 + kk4 * 4];
            #pragma unroll
            for (int i = 0; i < 4; ++i) {
                float xa = xs[(lane) * 17 + kk4 * 4 + i];
                float xb = xs[(64 + lane) * 17 + kk4 * 4 + i];
                #pragma unroll
                for (int c = 0; c < 10; ++c) {
                    float wc = (i == 0) ? wv[c].x : (i == 1) ? wv[c].y
                             : (i == 2) ? wv[c].z : wv[c].w;
                    acc[0][c] = fmaf(xa, wc, acc[0][c]);
                    acc[1][c] = fmaf(xb, wc, acc[1][c]);
                }
            }
        }
    }

    #pragma unroll
    for (int rr = 0; rr < 2; ++rr) {
        int r = rbase + rr * 64 + lane;
        if (r < N_NODES) {
            #pragma unroll
            for (int c2 = 0; c2 < 5; ++c2) {
                float2 o;
                o.x = acc[rr][c2 * 2 + 0] + fcb[w * 10 + c2 * 2 + 0];
                o.y = acc[rr][c2 * 2 + 1] + fcb[w * 10 + c2 * 2 + 1];
                *(float2*)(out + (size_t)r * 40 + w * 10 + c2 * 2) = o;
            }
        }
    }
}

// ---------------------------------------------------------------------------
extern "C" void kernel_launch(void* const* d_in, const int* in_sizes, int n_in,
                              void* d_out, int out_size, void* d_ws, size_t ws_size,
                              hipStream_t stream) {
    const float* x   = (const float*)d_in[0];
    const int*   ei  = (const int*)d_in[1];
    const int* e_row = ei;
    const int* e_col = ei + N_EDGES;
    const float* W1  = (const float*)d_in[2];
    const float* b1  = (const float*)d_in[3];
    const float* W2  = (const float*)d_in[4];
    const float* b2  = (const float*)d_in[5];
    const float* g1  = (const float*)d_in[6];
    const float* be1 = (const float*)d_in[7];
    const float* m1  = (const float*)d_in[8];
    const float* v1  = (const float*)d_in[9];
    const float* g2  = (const float*)d_in[10];
    const float* be2 = (const float*)d_in[11];
    const float* m2  = (const float*)d_in[12];
    const float* v2  = (const float*)d_in[13];
    const float* fcW = (const float*)d_in[14];
    const float* fcb = (const float*)d_in[15];
    float* out = (float*)d_out;

    char* ws = (char*)d_ws;
    size_t off = 0;
    auto alloc = [&](size_t b) {
        char* p = ws + off;
        off += (b + 255) & ~(size_t)255;
        return p;
    };
    uint*  h      = (uint*)alloc((size_t)N_NODES * C_H * 2);     // bf16 Hs
    float* x1     = (float*)alloc((size_t)N_NODES * C_H * 4);
    float* x2     = (float*)alloc((size_t)N_NODES * C_H * 4);
    int2*  pairs  = (int2*)alloc((size_t)N_EDGES * 8);
    int*   cols   = (int*)alloc((size_t)N_EDGES * 4);
    float* dinv   = (float*)alloc(N_NODES * 4);
    int*   rowptr = (int*)alloc((N_NODES + 1) * 4);
    int*   bcnt   = (int*)alloc((NB + 1) * 4);
    int*   bstart = (int*)alloc((NB + 1) * 4);
    int*   bfill  = (int*)alloc((NB + 1) * 4);
    float* coef   = (float*)alloc(512 * 4);
    float* s1 = coef, *t1 = coef + 128, *s2 = coef + 256, *t2 = coef + 384;

    const int nwg_bin = (N_EDGES + CHUNK - 1) / CHUNK;   // 261

    zero_i32<<<2, 256, 0, stream>>>(bcnt, NB);
    bucket_count<<<nwg_bin, 256, 0, stream>>>(e_row, bcnt);
    scan_buckets<<<1, 256, 0, stream>>>(bcnt, bstart, bfill);
    bucket_bin<<<nwg_bin, 256, 0, stream>>>(e_row, e_col, bfill, pairs);
    bucket_csr<<<NB, 256, 0, stream>>>(pairs, bstart, rowptr, dinv, cols);
    bn_coef<<<1, 128, 0, stream>>>(b1, g1, be1, m1, v1, b2, g2, be2, m2, v2,
                                   s1, t1, s2, t2);

    gemm_scaled<<<N_NODES / 32, 256, 0, stream>>>(x, W1, dinv, h);
    spmm_bn_relu3<<<N_NODES / 4, 256, 0, stream>>>(h, cols, rowptr, dinv, s1, t1, x1);
    gemm_scaled<<<N_NODES / 32, 256, 0, stream>>>(x1, W2, dinv, h);
    spmm_bn_relu3<<<N_NODES / 4, 256, 0, stream>>>(h, cols, rowptr, dinv, s2, t2, x2);
    final_gemm5<<<(N_NODES + 127) / 128, 256, 0, stream>>>(x, x1, x2, fcW, fcb, out);
}

// Round 8
// 511.442 us; speedup vs baseline: 1.5025x; 1.0592x over previous
//
#include <hip/hip_runtime.h>

#define N_NODES 100000
#define N_EDGES 1600000
#define C_H     128
#define C_OUT   40
#define K_FC    384
#define BN_EPS  1e-5f
#define NB      391        // buckets: row >> 8
#define CHUNK   6144       // edges per binning workgroup

typedef unsigned int uint;

// ---------------------------------------------------------------- utilities
__global__ void zero_i32(int* p, int n) {
    int i = blockIdx.x * blockDim.x + threadIdx.x;
    if (i < n) p[i] = 0;
}

// -------- CSR build, stage 1: per-chunk LDS histogram over 391 buckets
__global__ __launch_bounds__(256) void bucket_count(const int* __restrict__ erow,
                                                    int* __restrict__ bcnt) {
    __shared__ int cnt[NB];
    for (int i = threadIdx.x; i < NB; i += 256) cnt[i] = 0;
    __syncthreads();
    const int c0 = blockIdx.x * CHUNK;
    const int c1 = min(c0 + CHUNK, N_EDGES);
    for (int e = c0 + threadIdx.x; e < c1; e += 256)
        atomicAdd(&cnt[erow[e] >> 8], 1);
    __syncthreads();
    for (int i = threadIdx.x; i < NB; i += 256)
        if (cnt[i]) atomicAdd(&bcnt[i], cnt[i]);
}

// -------- stage 2: exclusive scan of bucket counts (single WG)
__global__ __launch_bounds__(256) void scan_buckets(const int* __restrict__ bcnt,
                                                    int* __restrict__ bstart,
                                                    int* __restrict__ bfill) {
    __shared__ int sa[512], sb[512];
    const int t = threadIdx.x;
    int v0 = (t < NB) ? bcnt[t] : 0;
    int v1 = (t + 256 < NB) ? bcnt[t + 256] : 0;
    sa[t] = v0; sa[t + 256] = v1;
    __syncthreads();
    int* src = sa; int* dst = sb;
    for (int off = 1; off < 512; off <<= 1) {
        dst[t]       = src[t]       + (t >= off ? src[t - off] : 0);
        dst[t + 256] = src[t + 256] + (t + 256 >= off ? src[t + 256 - off] : 0);
        __syncthreads();
        int* tmp = src; src = dst; dst = tmp;
    }
    if (t < NB)       { bstart[t] = src[t] - v0;             bfill[t] = src[t] - v0; }
    if (t + 256 < NB) { bstart[t + 256] = src[t + 256] - v1; bfill[t + 256] = src[t + 256] - v1; }
    if (t == 0) bstart[NB] = N_EDGES;
}

// -------- stage 3: scatter (row,col) pairs into per-bucket dense ranges
__global__ __launch_bounds__(256) void bucket_bin(const int* __restrict__ erow,
                                                  const int* __restrict__ ecol,
                                                  int* __restrict__ bfill,
                                                  int2* __restrict__ pairs) {
    __shared__ int cnt[NB];
    __shared__ int lpos[NB];
    for (int i = threadIdx.x; i < NB; i += 256) cnt[i] = 0;
    __syncthreads();
    const int c0 = blockIdx.x * CHUNK;
    const int c1 = min(c0 + CHUNK, N_EDGES);
    for (int e = c0 + threadIdx.x; e < c1; e += 256)
        atomicAdd(&cnt[erow[e] >> 8], 1);
    __syncthreads();
    for (int i = threadIdx.x; i < NB; i += 256)
        lpos[i] = cnt[i] ? atomicAdd(&bfill[i], cnt[i]) : 0;
    __syncthreads();
    for (int e = c0 + threadIdx.x; e < c1; e += 256) {
        int r = erow[e], c = ecol[e];
        int p = atomicAdd(&lpos[r >> 8], 1);
        pairs[p] = make_int2(r, c);
    }
}

// -------- stage 4: per-bucket local sort -> rowptr, dinv, cols (one WG/bucket)
__global__ __launch_bounds__(256) void bucket_csr(const int2* __restrict__ pairs,
                                                  const int* __restrict__ bstart,
                                                  int* __restrict__ rowptr,
                                                  float* __restrict__ dinv,
                                                  int* __restrict__ colsg) {
    __shared__ int lcnt[256], sa[256], sb[256], lpos[256];
    const int b = blockIdx.x;
    const int t = threadIdx.x;
    const int p0 = bstart[b], p1 = bstart[b + 1];
    lcnt[t] = 0;
    __syncthreads();
    for (int i = p0 + t; i < p1; i += 256)
        atomicAdd(&lcnt[pairs[i].x & 255], 1);
    __syncthreads();
    sa[t] = lcnt[t];
    __syncthreads();
    int* src = sa; int* dst = sb;
    for (int off = 1; off < 256; off <<= 1) {
        dst[t] = src[t] + (t >= off ? src[t - off] : 0);
        __syncthreads();
        int* tmp = src; src = dst; dst = tmp;
    }
    const int excl = src[t] - lcnt[t];
    const int r = b * 256 + t;
    if (r < N_NODES) {
        rowptr[r] = p0 + excl;
        dinv[r] = rsqrtf((float)lcnt[t] + 1.0f);
    }
    if (b == NB - 1 && t == 0) rowptr[N_NODES] = N_EDGES;
    lpos[t] = excl;
    __syncthreads();
    for (int i = p0 + t; i < p1; i += 256) {
        int2 pr = pairs[i];
        int s = atomicAdd(&lpos[pr.x & 255], 1);
        colsg[p0 + s] = pr.y;
    }
}

// relu(bn(agg + b)) = relu(agg*s + t)
__global__ void bn_coef(const float* b1, const float* g1, const float* be1,
                        const float* m1, const float* v1,
                        const float* b2, const float* g2, const float* be2,
                        const float* m2, const float* v2,
                        float* s1, float* t1, float* s2, float* t2) {
    int f = threadIdx.x;
    float sa = g1[f] * rsqrtf(v1[f] + BN_EPS);
    s1[f] = sa;
    t1[f] = (b1[f] - m1[f]) * sa + be1[f];
    float sb = g2[f] * rsqrtf(v2[f] + BN_EPS);
    s2[f] = sb;
    t2[f] = (b2[f] - m2[f]) * sb + be2[f];
}

#define FMA4(A, S, V) \
    A.x = fmaf(S, V.x, A.x); A.y = fmaf(S, V.y, A.y); \
    A.z = fmaf(S, V.z, A.z); A.w = fmaf(S, V.w, A.w);

__device__ inline uint pack_bf16x2(float a, float b) {
    uint ua = __builtin_bit_cast(uint, a);
    uint ub = __builtin_bit_cast(uint, b);
    ua += 0x7fffu + ((ua >> 16) & 1u);   // RNE
    ub += 0x7fffu + ((ub >> 16) & 1u);
    return (ua >> 16) | (ub & 0xffff0000u);
}

// -------------------- GEMM + dinv prescale: Hs(bf16) = diag(dinv) * (X @ W)
__global__ __launch_bounds__(256) void gemm_scaled(const float* __restrict__ X,
                                                   const float* __restrict__ W,
                                                   const float* __restrict__ dinv,
                                                   uint* __restrict__ Hs) {
    __shared__ float wl[64 * 128];   // k-half of W  (32 KB)
    __shared__ float xl[32 * 68];    // 32 rows x 64 cols, stride 68

    const int tid = threadIdx.x;
    const int rg = tid >> 5;
    const int c4 = (tid & 31) << 2;
    const int rb = blockIdx.x * 32;
    const int r0 = rb + rg * 4;

    float4 acc0 = {0,0,0,0}, acc1 = {0,0,0,0}, acc2 = {0,0,0,0}, acc3 = {0,0,0,0};

    for (int half = 0; half < 2; ++half) {
        const int k0 = half * 64;
        __syncthreads();
        {
            const float4* W4 = (const float4*)(W + (size_t)k0 * 128);
            float4* wl4 = (float4*)wl;
            #pragma unroll
            for (int i = 0; i < 8; ++i) wl4[tid + i * 256] = W4[tid + i * 256];
        }
        #pragma unroll
        for (int i = 0; i < 2; ++i) {
            int f = tid + i * 256;
            int row = f >> 4, cc = f & 15;
            float4 v = *(const float4*)(X + (size_t)(rb + row) * 128 + k0 + cc * 4);
            *(float4*)&xl[row * 68 + cc * 4] = v;
        }
        __syncthreads();

        for (int k4 = 0; k4 < 16; ++k4) {
            const float* wr = wl + k4 * 4 * 128 + c4;
            float4 w0 = *(const float4*)(wr);
            float4 w1 = *(const float4*)(wr + 128);
            float4 w2 = *(const float4*)(wr + 256);
            float4 w3 = *(const float4*)(wr + 384);
            float4 xv0 = *(const float4*)&xl[(rg * 4 + 0) * 68 + k4 * 4];
            float4 xv1 = *(const float4*)&xl[(rg * 4 + 1) * 68 + k4 * 4];
            float4 xv2 = *(const float4*)&xl[(rg * 4 + 2) * 68 + k4 * 4];
            float4 xv3 = *(const float4*)&xl[(rg * 4 + 3) * 68 + k4 * 4];
            FMA4(acc0, xv0.x, w0) FMA4(acc0, xv0.y, w1) FMA4(acc0, xv0.z, w2) FMA4(acc0, xv0.w, w3)
            FMA4(acc1, xv1.x, w0) FMA4(acc1, xv1.y, w1) FMA4(acc1, xv1.z, w2) FMA4(acc1, xv1.w, w3)
            FMA4(acc2, xv2.x, w0) FMA4(acc2, xv2.y, w1) FMA4(acc2, xv2.z, w2) FMA4(acc2, xv2.w, w3)
            FMA4(acc3, xv3.x, w0) FMA4(acc3, xv3.y, w1) FMA4(acc3, xv3.z, w2) FMA4(acc3, xv3.w, w3)
        }
    }
    float d0 = dinv[r0], d1 = dinv[r0 + 1], d2 = dinv[r0 + 2], d3 = dinv[r0 + 3];
    uint2 o;
    o.x = pack_bf16x2(acc0.x * d0, acc0.y * d0);
    o.y = pack_bf16x2(acc0.z * d0, acc0.w * d0);
    *(uint2*)(Hs + (size_t)(r0 + 0) * 64 + (c4 >> 1)) = o;
    o.x = pack_bf16x2(acc1.x * d1, acc1.y * d1);
    o.y = pack_bf16x2(acc1.z * d1, acc1.w * d1);
    *(uint2*)(Hs + (size_t)(r0 + 1) * 64 + (c4 >> 1)) = o;
    o.x = pack_bf16x2(acc2.x * d2, acc2.y * d2);
    o.y = pack_bf16x2(acc2.z * d2, acc2.w * d2);
    *(uint2*)(Hs + (size_t)(r0 + 2) * 64 + (c4 >> 1)) = o;
    o.x = pack_bf16x2(acc3.x * d3, acc3.y * d3);
    o.y = pack_bf16x2(acc3.z * d3, acc3.w * d3);
    *(uint2*)(Hs + (size_t)(r0 + 3) * 64 + (c4 >> 1)) = o;
}

// -------------------- SpMM on prescaled bf16 Hs: one wave per row, 2ch/lane.
// 16-deep gather pipeline, then 4, then 1.
#define ACC1(V) \
    accx += __builtin_bit_cast(float, V << 16); \
    accy += __builtin_bit_cast(float, V & 0xffff0000u);

__global__ __launch_bounds__(256) void spmm_bn_relu4(
    const uint* __restrict__ Hs, const int* __restrict__ cols,
    const int* __restrict__ rowptr, const float* __restrict__ dinv,
    const float* __restrict__ s, const float* __restrict__ t,
    float* __restrict__ Y) {
    const int lane = threadIdx.x & 63;
    const int r = blockIdx.x * 4 + (threadIdx.x >> 6);

    uint vself = Hs[(size_t)r * 64 + lane];
    float accx = __builtin_bit_cast(float, vself << 16);
    float accy = __builtin_bit_cast(float, vself & 0xffff0000u);
    const float di = dinv[r];
    const int e0 = rowptr[r], e1 = rowptr[r + 1];
    int j = e0;
    const int n16 = e0 + ((e1 - e0) & ~15);
    for (; j < n16; j += 16) {
        uint v[16];
        #pragma unroll
        for (int q = 0; q < 16; ++q)
            v[q] = Hs[(size_t)cols[j + q] * 64 + lane];
        #pragma unroll
        for (int q = 0; q < 16; ++q) { ACC1(v[q]) }
    }
    const int n4 = e0 + ((e1 - e0) & ~3);
    for (; j < n4; j += 4) {
        uint v[4];
        #pragma unroll
        for (int q = 0; q < 4; ++q)
            v[q] = Hs[(size_t)cols[j + q] * 64 + lane];
        #pragma unroll
        for (int q = 0; q < 4; ++q) { ACC1(v[q]) }
    }
    for (; j < e1; ++j) {
        uint v0 = Hs[(size_t)cols[j] * 64 + lane];
        ACC1(v0)
    }
    float2 sf = ((const float2*)s)[lane];
    float2 tf = ((const float2*)t)[lane];
    float2 o;
    o.x = fmaxf(fmaf(accx * di, sf.x, tf.x), 0.0f);
    o.y = fmaxf(fmaf(accy * di, sf.y, tf.y), 0.0f);
    ((float2*)Y)[(size_t)r * 64 + lane] = o;
}

// -------------------- final FC: out = [x0|x1|x2] @ fcW + fcb  (384 -> 40)
// Software-pipelined: chunk ch+1 staged into registers while computing chunk
// ch from LDS; double-buffered xs/wt; ONE __syncthreads per chunk.
// wt staged with linear address map (addr = idx) -> conflict-free writes.
__global__ __launch_bounds__(256) void final_gemm6(
    const float* __restrict__ X0, const float* __restrict__ X1,
    const float* __restrict__ X2, const float* __restrict__ fcW,
    const float* __restrict__ fcb, float* __restrict__ out) {
    __shared__ float xs[2][128 * 17];   // 2 x 8704 B
    __shared__ float wt[2][640];        // 2 x 2560 B, layout wt[c*16+kk]

    const int t = threadIdx.x;
    const int lane = t & 63;
    const int w = t >> 6;               // col group: cols w*10 .. w*10+9
    const int rbase = blockIdx.x * 128;

    float acc[2][10];
    #pragma unroll
    for (int rr = 0; rr < 2; ++rr)
        #pragma unroll
        for (int c = 0; c < 10; ++c) acc[rr][c] = 0.0f;

    const float* segs[3] = {X0, X1, X2};

    float4 xr[2];
    float wr[3];

    auto load_chunk = [&](int ch) {
        const int k0 = ch * 16;
        const float* xseg = segs[k0 >> 7];
        const int koff = k0 & 127;
        #pragma unroll
        for (int i = 0; i < 2; ++i) {
            int f = t + i * 256;
            int row = f >> 2, cc = f & 3;
            int r = rbase + row;
            float4 v = {0, 0, 0, 0};
            if (r < N_NODES)
                v = *(const float4*)(xseg + (size_t)r * 128 + koff + cc * 4);
            xr[i] = v;
        }
        #pragma unroll
        for (int i = 0; i < 3; ++i) {
            int idx = t + i * 256;
            float v = 0.0f;
            if (idx < 640) {
                int c = idx >> 4, kk = idx & 15;      // addr = idx (linear)
                v = fcW[(size_t)(k0 + kk) * 40 + c];
            }
            wr[i] = v;
        }
    };

    auto store_chunk = [&](int buf) {
        #pragma unroll
        for (int i = 0; i < 2; ++i) {
            int f = t + i * 256;
            int row = f >> 2, cc = f & 3;
            xs[buf][row * 17 + cc * 4 + 0] = xr[i].x;
            xs[buf][row * 17 + cc * 4 + 1] = xr[i].y;
            xs[buf][row * 17 + cc * 4 + 2] = xr[i].z;
            xs[buf][row * 17 + cc * 4 + 3] = xr[i].w;
        }
        #pragma unroll
        for (int i = 0; i < 3; ++i) {
            int idx = t + i * 256;
            if (idx < 640) wt[buf][idx] = wr[i];      // linear: conflict-free
        }
    };

    load_chunk(0);
    for (int ch = 0; ch < 24; ++ch) {
        const int buf = ch & 1;
        store_chunk(buf);
        if (ch < 23) load_chunk(ch + 1);   // in flight during compute below
        __syncthreads();
        #pragma unroll
        for (int kk4 = 0; kk4 < 4; ++kk4) {
            float4 wv[10];
            #pragma unroll
            for (int c = 0; c < 10; ++c)
                wv[c] = *(const float4*)&wt[buf][(w * 10 + c) * 16 + kk4 * 4];
            #pragma unroll
            for (int i = 0; i < 4; ++i) {
                float xa = xs[buf][(lane) * 17 + kk4 * 4 + i];
                float xb = xs[buf][(64 + lane) * 17 + kk4 * 4 + i];
                #pragma unroll
                for (int c = 0; c < 10; ++c) {
                    float wc = (i == 0) ? wv[c].x : (i == 1) ? wv[c].y
                             : (i == 2) ? wv[c].z : wv[c].w;
                    acc[0][c] = fmaf(xa, wc, acc[0][c]);
                    acc[1][c] = fmaf(xb, wc, acc[1][c]);
                }
            }
        }
        // no trailing sync: next iteration writes the OTHER buffer, whose
        // readers (compute of ch-1) all passed this iteration's barrier.
    }

    #pragma unroll
    for (int rr = 0; rr < 2; ++rr) {
        int r = rbase + rr * 64 + lane;
        if (r < N_NODES) {
            #pragma unroll
            for (int c2 = 0; c2 < 5; ++c2) {
                float2 o;
                o.x = acc[rr][c2 * 2 + 0] + fcb[w * 10 + c2 * 2 + 0];
                o.y = acc[rr][c2 * 2 + 1] + fcb[w * 10 + c2 * 2 + 1];
                *(float2*)(out + (size_t)r * 40 + w * 10 + c2 * 2) = o;
            }
        }
    }
}

// ---------------------------------------------------------------------------
extern "C" void kernel_launch(void* const* d_in, const int* in_sizes, int n_in,
                              void* d_out, int out_size, void* d_ws, size_t ws_size,
                              hipStream_t stream) {
    const float* x   = (const float*)d_in[0];
    const int*   ei  = (const int*)d_in[1];
    const int* e_row = ei;
    const int* e_col = ei + N_EDGES;
    const float* W1  = (const float*)d_in[2];
    const float* b1  = (const float*)d_in[3];
    const float* W2  = (const float*)d_in[4];
    const float* b2  = (const float*)d_in[5];
    const float* g1  = (const float*)d_in[6];
    const float* be1 = (const float*)d_in[7];
    const float* m1  = (const float*)d_in[8];
    const float* v1  = (const float*)d_in[9];
    const float* g2  = (const float*)d_in[10];
    const float* be2 = (const float*)d_in[11];
    const float* m2  = (const float*)d_in[12];
    const float* v2  = (const float*)d_in[13];
    const float* fcW = (const float*)d_in[14];
    const float* fcb = (const float*)d_in[15];
    float* out = (float*)d_out;

    char* ws = (char*)d_ws;
    size_t off = 0;
    auto alloc = [&](size_t b) {
        char* p = ws + off;
        off += (b + 255) & ~(size_t)255;
        return p;
    };
    uint*  h      = (uint*)alloc((size_t)N_NODES * C_H * 2);     // bf16 Hs
    float* x1     = (float*)alloc((size_t)N_NODES * C_H * 4);
    float* x2     = (float*)alloc((size_t)N_NODES * C_H * 4);
    int2*  pairs  = (int2*)alloc((size_t)N_EDGES * 8);
    int*   cols   = (int*)alloc((size_t)N_EDGES * 4);
    float* dinv   = (float*)alloc(N_NODES * 4);
    int*   rowptr = (int*)alloc((N_NODES + 1) * 4);
    int*   bcnt   = (int*)alloc((NB + 1) * 4);
    int*   bstart = (int*)alloc((NB + 1) * 4);
    int*   bfill  = (int*)alloc((NB + 1) * 4);
    float* coef   = (float*)alloc(512 * 4);
    float* s1 = coef, *t1 = coef + 128, *s2 = coef + 256, *t2 = coef + 384;

    const int nwg_bin = (N_EDGES + CHUNK - 1) / CHUNK;   // 261

    zero_i32<<<2, 256, 0, stream>>>(bcnt, NB);
    bucket_count<<<nwg_bin, 256, 0, stream>>>(e_row, bcnt);
    scan_buckets<<<1, 256, 0, stream>>>(bcnt, bstart, bfill);
    bucket_bin<<<nwg_bin, 256, 0, stream>>>(e_row, e_col, bfill, pairs);
    bucket_csr<<<NB, 256, 0, stream>>>(pairs, bstart, rowptr, dinv, cols);
    bn_coef<<<1, 128, 0, stream>>>(b1, g1, be1, m1, v1, b2, g2, be2, m2, v2,
                                   s1, t1, s2, t2);

    gemm_scaled<<<N_NODES / 32, 256, 0, stream>>>(x, W1, dinv, h);
    spmm_bn_relu4<<<N_NODES / 4, 256, 0, stream>>>(h, cols, rowptr, dinv, s1, t1, x1);
    gemm_scaled<<<N_NODES / 32, 256, 0, stream>>>(x1, W2, dinv, h);
    spmm_bn_relu4<<<N_NODES / 4, 256, 0, stream>>>(h, cols, rowptr, dinv, s2, t2, x2);
    final_gemm6<<<(N_NODES + 127) / 128, 256, 0, stream>>>(x, x1, x2, fcW, fcb, out);
}